// Round 1
// 501.338 us; speedup vs baseline: 1.2029x; 1.2029x over previous
//
#include <hip/hip_runtime.h>
#include <hip/hip_bf16.h>
#include <stdint.h>
#include <stddef.h>

// Problem constants (B=4, S=2048, D_IN=D_OUT=4096, r=16, scaling/r = 1.0)
#define D_IN   4096
#define D_OUT  4096
#define M_TOT  8192
#define R_RANK 16
#define LORA_SCALE 1.0f    // SCALING / R = 16/16

typedef __attribute__((ext_vector_type(8))) short short8;   // 8 x bf16 (4 VGPRs)
typedef __attribute__((ext_vector_type(4))) short short4v;  // 4 x bf16 (2 VGPRs)
typedef __attribute__((ext_vector_type(4))) float f32x4;    // MFMA accumulator

// async global->LDS, 16B per lane. LDS dest must be wave-uniform base + lane*16.
#define GL2LDS16(g, l)                                                  \
  __builtin_amdgcn_global_load_lds(                                     \
      (const __attribute__((address_space(1))) void*)(g),               \
      (__attribute__((address_space(3))) void*)(l), 16, 0, 0)

// ---------------------------------------------------------------------------
// prep_w: Wp[o][i] = bf16( W[o][i] + sum_r B[o][r]*c[r]*A[r][i] )  (unchanged)
// ---------------------------------------------------------------------------
__global__ __launch_bounds__(256) void prep_w(
    const float* __restrict__ W, const float* __restrict__ A,
    const float* __restrict__ c, const float* __restrict__ B,
    __hip_bfloat16* __restrict__ Wp) {
  int t  = threadIdx.x;
  int i  = blockIdx.x * 1024 + t * 4;
  int o0 = blockIdx.y * 4;

  float4 a4[R_RANK];
#pragma unroll
  for (int r = 0; r < R_RANK; r++) {
    float4 v = *(const float4*)(A + r * D_IN + i);
    float cr = c[r] * LORA_SCALE;
    v.x *= cr; v.y *= cr; v.z *= cr; v.w *= cr;
    a4[r] = v;
  }
#pragma unroll
  for (int oo = 0; oo < 4; oo++) {
    int o = o0 + oo;
    float4 w = *(const float4*)(W + (size_t)o * D_IN + i);
#pragma unroll
    for (int r = 0; r < R_RANK; r++) {
      float br = B[o * R_RANK + r];
      w.x += br * a4[r].x; w.y += br * a4[r].y;
      w.z += br * a4[r].z; w.w += br * a4[r].w;
    }
    __hip_bfloat16 tb[4];
    tb[0] = __float2bfloat16(w.x); tb[1] = __float2bfloat16(w.y);
    tb[2] = __float2bfloat16(w.z); tb[3] = __float2bfloat16(w.w);
    *(short4v*)(Wp + (size_t)o * D_IN + i) = *(const short4v*)tb;
  }
}

// ---------------------------------------------------------------------------
// pack_x: fp32 -> bf16, 8 elements/thread, 16B stores (unchanged)
// ---------------------------------------------------------------------------
__global__ __launch_bounds__(256) void pack_x(
    const float* __restrict__ x, __hip_bfloat16* __restrict__ Xp) {
  size_t idx = ((size_t)blockIdx.x * 256 + threadIdx.x) * 8;
  float4 v0 = *(const float4*)(x + idx);
  float4 v1 = *(const float4*)(x + idx + 4);
  __hip_bfloat16 t[8];
  t[0] = __float2bfloat16(v0.x); t[1] = __float2bfloat16(v0.y);
  t[2] = __float2bfloat16(v0.z); t[3] = __float2bfloat16(v0.w);
  t[4] = __float2bfloat16(v1.x); t[5] = __float2bfloat16(v1.y);
  t[6] = __float2bfloat16(v1.z); t[7] = __float2bfloat16(v1.w);
  *(short8*)(Xp + idx) = *(const short8*)t;
}

// ---------------------------------------------------------------------------
// gemm_256: 256x256 tile, BK=64, 512 threads (8 waves, 2Mx4N), 8-phase
// schedule with counted vmcnt (T3+T4), bank swizzle via pre-swizzled global
// source (T2, rule #21), setprio around MFMA clusters (T5).
//
// LDS layout: smem[buf][A|B][kh][256 rows][32 cols] bf16 — each K-half is a
// contiguous 16KiB block so global_load_lds deposits linearly (base+lane*16).
// Swizzle: physical chunk = logical chunk ^ ((row>>1)&3); per-thread this is
// compile-time-simple: reader chunk cph = kg ^ ((l15>>1)&3) (constant), and
// the staging source column applies the same involution.
//
// Phase schedule per K-tile t (buffer b = t&1, staging tile t+1 into b^1):
//   ph0: ds A[kh0,mh0](4)+B[kh0](4), stage A'kh0, bar, MFMA mh0, bar
//   ph1: ds A[kh0,mh1](4),           stage B'kh0, bar, MFMA mh1, vmcnt(4), bar
//   ph2: ds A[kh1,mh0](4)+B[kh1](4), stage A'kh1, bar, MFMA mh0, bar
//   ph3: ds A[kh1,mh1](4),           stage B'kh1, bar, MFMA mh1, vmcnt(4), bar
// vmcnt accounting (2 loads/thread/half-tile, ≤8 outstanding at each check):
//   ph1-end vmcnt(4) retires prev-tile's A'kh1+B'kh1  -> ph2/ph3 reads safe
//   ph3-end vmcnt(4) retires this-tile's A'kh0+B'kh0  -> next ph0/ph1 safe
// Loads are never drained to 0 in the main loop.
// ---------------------------------------------------------------------------
#define BK 64
#define NT (D_IN / BK)  // 64

#define SOFF(BUFI, AB, KH) ((((BUFI) * 2 + (AB)) * 2 + (KH)) * 8192)

#define VMCNT(N) asm volatile("s_waitcnt vmcnt(" #N ")" ::: "memory")
#define HARD_BARRIER() asm volatile("s_barrier" ::: "memory")
#define SOFT_BARRIER() __builtin_amdgcn_s_barrier()

// stage one half-tile (256 rows x 32 cols bf16 = 16KiB) of tile TS into
// smem block (BUFI, AB, KH). 2 x global_load_lds(16B) per thread.
#define STAGE_HALF(BUFI, AB, KH, TS)                                         \
  do {                                                                       \
    const __hip_bfloat16* _src = (AB) ? Wp : Xp;                             \
    const int _rb = (AB) ? n0 : m0;                                          \
    const int _kb = (TS) * BK + (KH) * 32;                                   \
    _Pragma("unroll")                                                        \
    for (int _is = 0; _is < 2; ++_is) {                                      \
      const int _p = _is * 512 + tid;   /* chunk 0..1023 */                  \
      const int _row = _p >> 2;                                              \
      const int _c = (_p & 3) ^ ((_row >> 1) & 3); /* inverse swizzle */     \
      GL2LDS16(_src + (size_t)(_rb + _row) * D_IN + _kb + _c * 8,            \
               smem + SOFF(BUFI, AB, KH) + _p * 8);                          \
    }                                                                        \
  } while (0)

#define LOAD_AF(BUFI, KH, MH)                                                \
  _Pragma("unroll")                                                          \
  for (int _j = 0; _j < 4; ++_j)                                             \
    af[_j] = *(const short8*)(smem + SOFF(BUFI, 0, KH) +                     \
                              (wm * 128 + ((MH) * 4 + _j) * 16 + l15) * 32 + \
                              cph * 8);

#define LOAD_BF(BUFI, KH)                                                    \
  _Pragma("unroll")                                                          \
  for (int _nn = 0; _nn < 4; ++_nn)                                          \
    bf[_nn] = *(const short8*)(smem + SOFF(BUFI, 1, KH) +                    \
                               (wn * 64 + _nn * 16 + l15) * 32 + cph * 8);

#define MFMA_HALF(MH)                                                        \
  do {                                                                       \
    __builtin_amdgcn_s_setprio(1);                                           \
    _Pragma("unroll")                                                        \
    for (int _j = 0; _j < 4; ++_j)                                           \
      _Pragma("unroll")                                                      \
      for (int _nn = 0; _nn < 4; ++_nn)                                      \
        acc[(MH) * 4 + _j][_nn] = __builtin_amdgcn_mfma_f32_16x16x32_bf16(   \
            af[_j], bf[_nn], acc[(MH) * 4 + _j][_nn], 0, 0, 0);              \
    __builtin_amdgcn_s_setprio(0);                                           \
  } while (0)

// DO_STAGE is a compile-time literal 0/1.
#define TILE_BODY(BUFI, NBUF, T, DO_STAGE)                                   \
  do {                                                                       \
    /* ph0: kh=0, mh=0 */                                                    \
    LOAD_AF(BUFI, 0, 0);                                                     \
    LOAD_BF(BUFI, 0);                                                        \
    if (DO_STAGE) STAGE_HALF(NBUF, 0, 0, (T) + 1);                           \
    SOFT_BARRIER();                                                          \
    MFMA_HALF(0);                                                            \
    SOFT_BARRIER();                                                          \
    /* ph1: kh=0, mh=1 */                                                    \
    LOAD_AF(BUFI, 0, 1);                                                     \
    if (DO_STAGE) STAGE_HALF(NBUF, 1, 0, (T) + 1);                           \
    SOFT_BARRIER();                                                          \
    MFMA_HALF(1);                                                            \
    if (DO_STAGE) { VMCNT(4); } else { VMCNT(0); }                           \
    HARD_BARRIER();                                                          \
    /* ph2: kh=1, mh=0 */                                                    \
    LOAD_AF(BUFI, 1, 0);                                                     \
    LOAD_BF(BUFI, 1);                                                        \
    if (DO_STAGE) STAGE_HALF(NBUF, 0, 1, (T) + 1);                           \
    SOFT_BARRIER();                                                          \
    MFMA_HALF(0);                                                            \
    SOFT_BARRIER();                                                          \
    /* ph3: kh=1, mh=1 */                                                    \
    LOAD_AF(BUFI, 1, 1);                                                     \
    if (DO_STAGE) STAGE_HALF(NBUF, 1, 1, (T) + 1);                           \
    SOFT_BARRIER();                                                          \
    MFMA_HALF(1);                                                            \
    if (DO_STAGE) { VMCNT(4); } else { VMCNT(0); }                           \
    HARD_BARRIER();                                                          \
  } while (0)

__global__ __launch_bounds__(512, 2) void gemm_256(
    const __hip_bfloat16* __restrict__ Xp,
    const __hip_bfloat16* __restrict__ Wp,
    const float* __restrict__ bias,
    float* __restrict__ out) {
  // 2 bufs x {A,B} x {kh0,kh1} x 256x32 bf16 = 128 KiB (1 block/CU)
  __shared__ __align__(16) __hip_bfloat16 smem[2 * 2 * 2 * 8192];

  const int tid  = threadIdx.x;
  const int wid  = tid >> 6;
  const int lane = tid & 63;
  const int wm = wid >> 2;            // 0..1  (M half: 128 rows)
  const int wn = wid & 3;             // 0..3  (N quarter: 64 cols)
  const int l15 = lane & 15;
  const int kg  = lane >> 4;          // 0..3
  const int cph = kg ^ ((l15 >> 1) & 3);  // swizzled read chunk (const/thread)
  const int m0 = blockIdx.y * 256;
  const int n0 = blockIdx.x * 256;

  f32x4 acc[8][4];
#pragma unroll
  for (int i = 0; i < 8; i++)
#pragma unroll
    for (int j = 0; j < 4; j++) acc[i][j] = (f32x4){0.f, 0.f, 0.f, 0.f};

  short8 af[4];
  short8 bf[4];

  // Prologue: stage tile 0 -> buf0, consumption-priority order.
  STAGE_HALF(0, 0, 0, 0);  // A kh0
  STAGE_HALF(0, 1, 0, 0);  // B kh0
  STAGE_HALF(0, 0, 1, 0);  // A kh1
  STAGE_HALF(0, 1, 1, 0);  // B kh1
  VMCNT(4);                // A/B kh0 landed; kh1 still in flight
  HARD_BARRIER();

#pragma unroll 1
  for (int t = 0; t < NT - 2; t += 2) {
    TILE_BODY(0, 1, t, 1);       // compute buf0 (tile t),   stage t+1 -> buf1
    TILE_BODY(1, 0, t + 1, 1);   // compute buf1 (tile t+1), stage t+2 -> buf0
  }
  TILE_BODY(0, 1, NT - 2, 1);    // tile 62, stages tile 63 -> buf1
  TILE_BODY(1, 0, NT - 1, 0);    // tile 63, epilogue (drain with vmcnt(0))

  // Epilogue: C/D layout col = lane&15 (n), row = (lane>>4)*4+reg (m); + bias
  float bv[4];
#pragma unroll
  for (int nn = 0; nn < 4; ++nn) bv[nn] = bias[n0 + wn * 64 + nn * 16 + l15];
#pragma unroll
  for (int mm = 0; mm < 8; ++mm) {
#pragma unroll
    for (int reg = 0; reg < 4; ++reg) {
      const int row = m0 + wm * 128 + mm * 16 + kg * 4 + reg;
      float* po = out + (size_t)row * D_OUT + n0 + wn * 64 + l15;
#pragma unroll
      for (int nn = 0; nn < 4; ++nn) po[nn * 16] = acc[mm][nn][reg] + bv[nn];
    }
  }
}

// ---------------------------------------------------------------------------
extern "C" void kernel_launch(void* const* d_in, const int* in_sizes, int n_in,
                              void* d_out, int out_size, void* d_ws, size_t ws_size,
                              hipStream_t stream) {
  const float* x  = (const float*)d_in[0];   // [4,2048,4096]
  const float* W  = (const float*)d_in[1];   // [4096,4096]
  const float* b  = (const float*)d_in[2];   // [4096]
  const float* lA = (const float*)d_in[3];   // [16,4096]
  const float* lB = (const float*)d_in[4];   // [4096,16]
  const float* lc = (const float*)d_in[5];   // [16,1]
  float* out = (float*)d_out;                // [4,2048,4096] fp32

  char* ws = (char*)d_ws;
  __hip_bfloat16* Xp = (__hip_bfloat16*)ws;                       // 64 MiB
  __hip_bfloat16* Wp = (__hip_bfloat16*)(ws + (size_t)67108864);  // 32 MiB

  pack_x<<<dim3(M_TOT * D_IN / (256 * 8)), dim3(256), 0, stream>>>(x, Xp);
  prep_w<<<dim3(D_IN / 1024, D_OUT / 4), dim3(256), 0, stream>>>(W, lA, lc, lB, Wp);
  gemm_256<<<dim3(D_OUT / 256, M_TOT / 256), dim3(512), 0, stream>>>(Xp, Wp, b, out);
}